// Round 8
// baseline (161.473 us; speedup 1.0000x reference)
//
#include <hip/hip_runtime.h>
#include <hip/hip_bf16.h>

#define IN_DIM   27000
#define ENC_DIM  768
#define LATENT   128
#define K_CODES  512
#define BATCH    256
#define ZCH      288            // k_z split-K chunk (9 K-tiles of 32)
#define NZC      94             // ceil(27000/288); last chunk = 216
#define NWC      422            // k_wc blocks = ceil(27000/64)
#define BN_R     32
#define NRB      844            // k_recon blocks = ceil(27000/32)
#define PADK     40             // LDS k-pitch (ushorts)

// ---- d_out-region scratch (inside x_recon area, 6,912,000 f32 slots) ----
#define OUT_WCTH_US   0                       // ushort offset: [128][27000] hi
#define OUT_WCTL_US   (128*IN_DIM)            // ushort offset: [128][27000] lo
#define OUT_ZPART_F   (128*IN_DIM)            // f32 slot 3,456,000: [94][256][128]
// zpart end = 3,456,000 + 94*32768 = 6,536,192 < 6,912,000 (disjoint from WcT)

// ---- d_ws layout (f32 slots), ~858 KB ----
#define WS_Z      0                          // [256][128] f32
#define WS_QUANT  (WS_Z + BATCH*LATENT)      // [256][128] f32
#define WS_IDX    (WS_QUANT + BATCH*LATENT)  // int[256]
#define WS_VQPART (WS_IDX + BATCH)           // f32[256]
#define WS_RECON  (WS_VQPART + BATCH)        // f32[NRB] (reserve 1024)
#define WS_HBF    (WS_RECON + 1024)          // ushort[256*768] = 49152 slots
#define WS_WLH    (WS_HBF + 49152)           // ushort[128][768] hi (n-major)
#define WS_WLL    (WS_WLH + 49152)           // ushort[128][768] lo

typedef unsigned short ushort_t;
typedef __attribute__((ext_vector_type(4))) float f32x4;
typedef __attribute__((ext_vector_type(8))) short short8x;
typedef __attribute__((ext_vector_type(4))) short short4x;

__device__ __forceinline__ ushort_t bf16_rne(float f) {
    unsigned u = __float_as_uint(f);
    unsigned r = 0x7FFFu + ((u >> 16) & 1u);
    return (ushort_t)((u + r) >> 16);
}
// truncate-hi + rne-lo split: |v - (hi+lo)| <= 2^-17 |v|
__device__ __forceinline__ void split_f32(float v, ushort_t& h, ushort_t& l) {
    unsigned u  = __float_as_uint(v);
    unsigned uh = u & 0xFFFF0000u;
    h = (ushort_t)(uh >> 16);
    l = bf16_rne(v - __uint_as_float(uh));
}

// ============ Kernel 0: pre-split W_lat -> n-major bf16 hi/lo ============
__global__ __launch_bounds__(256) void k_prep(const float* __restrict__ Wlat,
                                              ushort_t* __restrict__ wlh,
                                              ushort_t* __restrict__ wll) {
    const int i4 = blockIdx.x * 256 + threadIdx.x;   // 0..24575
    const int k  = i4 >> 5;                          // 0..767
    const int n4 = (i4 & 31) * 4;
    float4 v = *(const float4*)(Wlat + (size_t)k * LATENT + n4);
    float vv[4] = {v.x, v.y, v.z, v.w};
#pragma unroll
    for (int j = 0; j < 4; j++) {
        ushort_t h, l;
        split_f32(vv[j], h, l);
        wlh[(size_t)(n4 + j) * ENC_DIM + k] = h;
        wll[(size_t)(n4 + j) * ENC_DIM + k] = l;
    }
}

// ============ Kernel 1: WcT = (W_enc @ W_lat)^T as split-bf16 ============
// M=27000, N=128, K=768. LDS double-buffered staging + reg prefetch.
__global__ __launch_bounds__(256) void k_wc(const float* __restrict__ Wenc,
                                            const ushort_t* __restrict__ wlh,
                                            const ushort_t* __restrict__ wll,
                                            ushort_t* __restrict__ wcth,
                                            ushort_t* __restrict__ wctl) {
    __shared__ ushort_t Ah[2][64][PADK], Al[2][64][PADK];    // [buf][m][k]
    __shared__ ushort_t Bh[2][128][PADK], Bl[2][128][PADK];  // [buf][n][k]
    const int t = threadIdx.x, lane = t & 63, w = t >> 6;
    const int lrow = lane & 15, kg = lane >> 4;
    const int m0 = blockIdx.x * 64;

    const int a_row = t >> 3, a_kq = t & 7;   // + p*32 rows; float4 kq
    const int b_n   = t >> 2, b_ck = t & 3;   // + p*64 n;    short8x ck

    float4  areg[2];
    short8x bhreg[2], blreg[2];

    f32x4 acc[8];
#pragma unroll
    for (int ni = 0; ni < 8; ni++) acc[ni] = (f32x4){0.f, 0.f, 0.f, 0.f};

    auto load_tile = [&](int kt) {
        const int k0 = kt * 32;
#pragma unroll
        for (int p = 0; p < 2; p++) {
            int r = m0 + a_row + p * 32; if (r > IN_DIM - 1) r = IN_DIM - 1;
            areg[p] = *(const float4*)(Wenc + (size_t)r * ENC_DIM + k0 + a_kq * 4);
        }
#pragma unroll
        for (int p = 0; p < 2; p++) {
            const size_t bo = (size_t)(b_n + p * 64) * ENC_DIM + k0 + b_ck * 8;
            bhreg[p] = *(const short8x*)(wlh + bo);
            blreg[p] = *(const short8x*)(wll + bo);
        }
    };
    auto store_tile = [&](int bi) {
#pragma unroll
        for (int p = 0; p < 2; p++) {
            const int row = a_row + p * 32;
            float vv[4] = {areg[p].x, areg[p].y, areg[p].z, areg[p].w};
            short4x h4, l4;
#pragma unroll
            for (int i = 0; i < 4; i++) {
                ushort_t h, l; split_f32(vv[i], h, l);
                h4[i] = (short)h; l4[i] = (short)l;
            }
            *(short4x*)&Ah[bi][row][a_kq * 4] = h4;
            *(short4x*)&Al[bi][row][a_kq * 4] = l4;
        }
#pragma unroll
        for (int p = 0; p < 2; p++) {
            const int n = b_n + p * 64;
            *(short8x*)&Bh[bi][n][b_ck * 8] = bhreg[p];
            *(short8x*)&Bl[bi][n][b_ck * 8] = blreg[p];
        }
    };

    load_tile(0);
    store_tile(0);
    __syncthreads();

    for (int kt = 0; kt < ENC_DIM / 32; kt++) {
        if (kt < ENC_DIM / 32 - 1) load_tile(kt + 1);
        const int bi = kt & 1;
        short8x ah = *(const short8x*)&Ah[bi][w * 16 + lrow][kg * 8];
        short8x al = *(const short8x*)&Al[bi][w * 16 + lrow][kg * 8];
#pragma unroll
        for (int ni = 0; ni < 8; ni++) {
            short8x bhf = *(const short8x*)&Bh[bi][ni * 16 + lrow][kg * 8];
            short8x blf = *(const short8x*)&Bl[bi][ni * 16 + lrow][kg * 8];
            acc[ni] = __builtin_amdgcn_mfma_f32_16x16x32_bf16(ah, bhf, acc[ni], 0, 0, 0);
            acc[ni] = __builtin_amdgcn_mfma_f32_16x16x32_bf16(ah, blf, acc[ni], 0, 0, 0);
            acc[ni] = __builtin_amdgcn_mfma_f32_16x16x32_bf16(al, bhf, acc[ni], 0, 0, 0);
        }
        if (kt < ENC_DIM / 32 - 1) store_tile((kt + 1) & 1);
        __syncthreads();
    }

    const int rowb = m0 + w * 16 + kg * 4;   // 4 | 27000: group fully valid or OOB
    if (rowb < IN_DIM) {
#pragma unroll
        for (int ni = 0; ni < 8; ni++) {
            const int col = ni * 16 + lrow;
            short4x h4, l4;
#pragma unroll
            for (int r = 0; r < 4; r++) {
                ushort_t h, l; split_f32(acc[ni][r], h, l);
                h4[r] = (short)h; l4[r] = (short)l;
            }
            *(short4x*)(wcth + (size_t)col * IN_DIM + rowb) = h4;
            *(short4x*)(wctl + (size_t)col * IN_DIM + rowb) = l4;
        }
    }
}

// ============ Kernel 2: zpart = x @ Wc (split-K, 94 chunks of 288) ============
__global__ __launch_bounds__(256) void k_z(const float* __restrict__ x,
                                           const ushort_t* __restrict__ wcth,
                                           const ushort_t* __restrict__ wctl,
                                           float* __restrict__ zpart) {
    __shared__ ushort_t Ah[2][64][PADK], Al[2][64][PADK];
    __shared__ ushort_t Bh[2][128][PADK], Bl[2][128][PADK];
    const int t = threadIdx.x, lane = t & 63, w = t >> 6;
    const int lrow = lane & 15, kg = lane >> 4;
    const int m0 = blockIdx.x * 64;                 // < 256
    const int c  = blockIdx.y;
    const int kb = c * ZCH;
    const int k_end = min(IN_DIM, kb + ZCH);
    const int nt = (k_end - kb + 31) >> 5;          // 9 (7 for last chunk)

    const int a_row = t >> 3, a_kq = t & 7;
    const int b_n   = t >> 2, b_ck = t & 3;

    float4  areg[2];
    short8x bhreg[2], blreg[2];

    f32x4 acc[8];
#pragma unroll
    for (int ni = 0; ni < 8; ni++) acc[ni] = (f32x4){0.f, 0.f, 0.f, 0.f};

    auto load_tile = [&](int kt) {
        const int k0 = kb + kt * 32;
#pragma unroll
        for (int p = 0; p < 2; p++) {
            const int kk = k0 + a_kq * 4;
            if (kk < k_end) {
                const int r = m0 + a_row + p * 32;
                areg[p] = *(const float4*)(x + (size_t)r * IN_DIM + kk);
            } else {
                areg[p] = (float4){0.f, 0.f, 0.f, 0.f};
            }
        }
#pragma unroll
        for (int p = 0; p < 2; p++) {
            const int kk = k0 + b_ck * 8;
            if (kk < k_end) {
                const size_t bo = (size_t)(b_n + p * 64) * IN_DIM + kk;
                bhreg[p] = *(const short8x*)(wcth + bo);
                blreg[p] = *(const short8x*)(wctl + bo);
            } else {
                short8x zz = {0, 0, 0, 0, 0, 0, 0, 0};
                bhreg[p] = zz; blreg[p] = zz;
            }
        }
    };
    auto store_tile = [&](int bi) {
#pragma unroll
        for (int p = 0; p < 2; p++) {
            const int row = a_row + p * 32;
            float vv[4] = {areg[p].x, areg[p].y, areg[p].z, areg[p].w};
            short4x h4, l4;
#pragma unroll
            for (int i = 0; i < 4; i++) {
                ushort_t h, l; split_f32(vv[i], h, l);
                h4[i] = (short)h; l4[i] = (short)l;
            }
            *(short4x*)&Ah[bi][row][a_kq * 4] = h4;
            *(short4x*)&Al[bi][row][a_kq * 4] = l4;
        }
#pragma unroll
        for (int p = 0; p < 2; p++) {
            const int n = b_n + p * 64;
            *(short8x*)&Bh[bi][n][b_ck * 8] = bhreg[p];
            *(short8x*)&Bl[bi][n][b_ck * 8] = blreg[p];
        }
    };

    load_tile(0);
    store_tile(0);
    __syncthreads();

    for (int kt = 0; kt < nt; kt++) {
        if (kt < nt - 1) load_tile(kt + 1);
        const int bi = kt & 1;
        short8x ah = *(const short8x*)&Ah[bi][w * 16 + lrow][kg * 8];
        short8x al = *(const short8x*)&Al[bi][w * 16 + lrow][kg * 8];
#pragma unroll
        for (int ni = 0; ni < 8; ni++) {
            short8x bhf = *(const short8x*)&Bh[bi][ni * 16 + lrow][kg * 8];
            short8x blf = *(const short8x*)&Bl[bi][ni * 16 + lrow][kg * 8];
            acc[ni] = __builtin_amdgcn_mfma_f32_16x16x32_bf16(ah, bhf, acc[ni], 0, 0, 0);
            acc[ni] = __builtin_amdgcn_mfma_f32_16x16x32_bf16(ah, blf, acc[ni], 0, 0, 0);
            acc[ni] = __builtin_amdgcn_mfma_f32_16x16x32_bf16(al, bhf, acc[ni], 0, 0, 0);
        }
        if (kt < nt - 1) store_tile((kt + 1) & 1);
        __syncthreads();
    }

    float* zp = zpart + (size_t)c * (BATCH * LATENT);
    const int rowb = m0 + w * 16 + kg * 4;
#pragma unroll
    for (int ni = 0; ni < 8; ni++) {
        const int col = ni * 16 + lrow;
#pragma unroll
        for (int r = 0; r < 4; r++)
            zp[(size_t)(rowb + r) * LATENT + col] = acc[ni][r];
    }
}

// ============ Kernel 3: z = sum(zpart) + bias ============
__global__ __launch_bounds__(256) void k_zred(const float* __restrict__ zpart,
                                              const float* __restrict__ blat,
                                              float* __restrict__ z) {
    const int o = blockIdx.x * 256 + threadIdx.x;   // < 32768
    float s = blat[o & (LATENT - 1)];
    for (int c = 0; c < NZC; c++) s += zpart[(size_t)c * (BATCH * LATENT) + o];
    z[o] = s;
}

// ============ Kernel 4: VQ — distances, argmin, gather, vq partial ============
__global__ __launch_bounds__(256) void k_vq(const float* __restrict__ z,
                                            const float* __restrict__ cb,
                                            float* __restrict__ quant,
                                            int* __restrict__ idx_out,
                                            float* __restrict__ vqpart) {
    __shared__ float zs[LATENT];
    __shared__ float ds_[256];
    __shared__ int   is_[256];
    const int b = blockIdx.x, t = threadIdx.x;
    if (t < LATENT) zs[t] = z[b * LATENT + t];
    __syncthreads();

    float best_d = 3.4e38f; int best_i = 0;
#pragma unroll
    for (int rep = 0; rep < 2; rep++) {
        const int k = t + rep * 256;
        const float* e = cb + (size_t)k * LATENT;
        float acc = 0.f;
#pragma unroll 4
        for (int d = 0; d < LATENT; d += 4) {
            float4 ev = *(const float4*)(e + d);
            float d0 = zs[d]   - ev.x;
            float d1 = zs[d+1] - ev.y;
            float d2 = zs[d+2] - ev.z;
            float d3 = zs[d+3] - ev.w;
            acc += d0*d0 + d1*d1 + d2*d2 + d3*d3;
        }
        if (acc < best_d) { best_d = acc; best_i = k; }
    }
    ds_[t] = best_d; is_[t] = best_i;
    __syncthreads();
    for (int s = 128; s > 0; s >>= 1) {
        if (t < s) {
            float od = ds_[t+s]; int oi = is_[t+s];
            if (od < ds_[t] || (od == ds_[t] && oi < is_[t])) { ds_[t] = od; is_[t] = oi; }
        }
        __syncthreads();
    }
    const int best = is_[0];
    if (t == 0) idx_out[b] = best;

    float sq = 0.f;
    if (t < LATENT) {
        float q = cb[(size_t)best * LATENT + t];
        quant[b * LATENT + t] = q;
        float dd = q - zs[t];
        sq = dd * dd;
    }
    __syncthreads();
    ds_[t] = sq;
    __syncthreads();
    for (int s = 128; s > 0; s >>= 1) {
        if (t < s) ds_[t] += ds_[t+s];
        __syncthreads();
    }
    if (t == 0) vqpart[b] = ds_[0];
}

// ============ Kernel 5: h = relu(quant @ W_d1 + b_d1) -> bf16 ============
__global__ __launch_bounds__(256) void k_h(const float* __restrict__ quant,
                                           const float* __restrict__ Wd1,
                                           const float* __restrict__ bd1,
                                           ushort_t* __restrict__ hbf) {
    const int bid = blockIdx.x, t = threadIdx.x;
    const int row = bid / 3;
    const int col = (bid % 3) * 256 + t;
    float acc = bd1[col];
    const float* q = quant + row * LATENT;
#pragma unroll 8
    for (int k = 0; k < LATENT; k++)
        acc = fmaf(q[k], Wd1[(size_t)k * ENC_DIM + col], acc);
    hbf[(size_t)row * ENC_DIM + col] = bf16_rne(fmaxf(acc, 0.f));
}

// ============ Kernel 6: x_recon = h @ W_d2 + b_d2 + fused loss ============
// BM=256 (full batch), BN=32 -> 844 blocks. A-frags per-lane direct from
// hbf (L2-resident). B double-buffered in LDS. 4 waves, wave = 64 rows x 32 cols.
__global__ __launch_bounds__(256) void k_recon_mfma(const ushort_t* __restrict__ hbf,
                                                    const float* __restrict__ Wd2,
                                                    const float* __restrict__ bd2,
                                                    const float* __restrict__ x,
                                                    float* __restrict__ out,
                                                    float* __restrict__ reconpart) {
    __shared__ ushort_t Bts[2][BN_R][PADK];   // [buf][n][k]
    __shared__ float red[256];
    const int t = threadIdx.x, lane = t & 63, wid = t >> 6;
    const int lrow = lane & 15, kg = lane >> 4;
    const int n0 = blockIdx.x * BN_R;

    const int b_k  = t >> 3;   // 0..31 (k-row within tile)
    const int b_nq = t & 7;    // 0..7  (4 cols each)

    f32x4 acc[4][2];
#pragma unroll
    for (int mi = 0; mi < 4; mi++)
#pragma unroll
        for (int ni = 0; ni < 2; ni++) acc[mi][ni] = (f32x4){0.f, 0.f, 0.f, 0.f};

    float4 breg;
    const int col0 = n0 + b_nq * 4;

    auto load_B = [&](int kt) {
        const float* wr = Wd2 + (size_t)(kt * 32 + b_k) * IN_DIM + col0;
        if (col0 + 3 < IN_DIM) {
            breg = *(const float4*)wr;
        } else {
            breg.x = (col0     < IN_DIM) ? wr[0] : 0.f;
            breg.y = (col0 + 1 < IN_DIM) ? wr[1] : 0.f;
            breg.z = (col0 + 2 < IN_DIM) ? wr[2] : 0.f;
            breg.w = (col0 + 3 < IN_DIM) ? wr[3] : 0.f;
        }
    };
    auto store_B = [&](int bi) {
        float vv[4] = {breg.x, breg.y, breg.z, breg.w};
#pragma unroll
        for (int i = 0; i < 4; i++)
            Bts[bi][b_nq * 4 + i][b_k] = bf16_rne(vv[i]);
    };

    load_B(0);
    store_B(0);
    __syncthreads();

    for (int kt = 0; kt < ENC_DIM / 32; kt++) {
        if (kt < ENC_DIM / 32 - 1) load_B(kt + 1);
        const int bi = kt & 1;
        short8x a[4], b[2];
#pragma unroll
        for (int mi = 0; mi < 4; mi++)
            a[mi] = *(const short8x*)(hbf + (size_t)(wid * 64 + mi * 16 + lrow) * ENC_DIM
                                      + kt * 32 + kg * 8);
#pragma unroll
        for (int ni = 0; ni < 2; ni++)
            b[ni] = *(const short8x*)&Bts[bi][ni * 16 + lrow][kg * 8];
#pragma unroll
        for (int mi = 0; mi < 4; mi++)
#pragma unroll
            for (int ni = 0; ni < 2; ni++)
                acc[mi][ni] = __builtin_amdgcn_mfma_f32_16x16x32_bf16(a[mi], b[ni], acc[mi][ni], 0, 0, 0);
        if (kt < ENC_DIM / 32 - 1) store_B((kt + 1) & 1);
        __syncthreads();
    }

    float lsq = 0.f;
#pragma unroll
    for (int mi = 0; mi < 4; mi++) {
        const int rowb = wid * 64 + mi * 16 + kg * 4;
#pragma unroll
        for (int ni = 0; ni < 2; ni++) {
            const int col = n0 + ni * 16 + lrow;
            if (col < IN_DIM) {
                const float bb = bd2[col];
#pragma unroll
                for (int r = 0; r < 4; r++) {
                    const int row = rowb + r;
                    float v = acc[mi][ni][r] + bb;
                    float e = v - x[(size_t)row * IN_DIM + col];
                    lsq += e * e;
                    out[(size_t)row * IN_DIM + col] = v;
                }
            }
        }
    }

    red[t] = lsq;
    __syncthreads();
    for (int s = 128; s > 0; s >>= 1) {
        if (t < s) red[t] += red[t + s];
        __syncthreads();
    }
    if (t == 0) reconpart[blockIdx.x] = red[0];
}

// ============ Kernel 7: finalize losses + indices (f32) ============
__global__ __launch_bounds__(256) void k_final(const float* __restrict__ reconpart,
                                               const float* __restrict__ vqpart,
                                               const int* __restrict__ idx,
                                               float* __restrict__ out,
                                               long long obase) {
    __shared__ float red[256];
    const int t = threadIdx.x;
    float s = 0.f;
    for (int i = t; i < NRB; i += 256) s += reconpart[i];
    red[t] = s;
    __syncthreads();
    for (int st = 128; st > 0; st >>= 1) {
        if (t < st) red[t] += red[t + st];
        __syncthreads();
    }
    const float recon_sum = red[0];
    __syncthreads();
    red[t] = vqpart[t];
    __syncthreads();
    for (int st = 128; st > 0; st >>= 1) {
        if (t < st) red[t] += red[t + st];
        __syncthreads();
    }
    const float vq_sum = red[0];
    if (t == 0) {
        float recon_loss = recon_sum / (float)((size_t)BATCH * IN_DIM);
        float vq_loss = 1.1f * vq_sum / (float)(BATCH * LATENT);
        out[obase + 0] = recon_loss + vq_loss;
        out[obase + 1] = vq_loss;
    }
    out[obase + 2 + t] = (float)idx[t];
}

extern "C" void kernel_launch(void* const* d_in, const int* in_sizes, int n_in,
                              void* d_out, int out_size, void* d_ws, size_t ws_size,
                              hipStream_t stream) {
    int ix = 0, iwe = 1, iwl = 2, ibl = 3, icb = 4, iwd1 = 5, ibd1 = 6, iwd2 = 7, ibd2 = 8;
    if (n_in == 9 && in_sizes[0] != BATCH * IN_DIM) {
        int p20[2] = {1, 7}, n20 = 0, p98[2] = {2, 5}, n98 = 0;
        for (int i = 0; i < 9; i++) {
            const int s = in_sizes[i];
            if      (s == BATCH * IN_DIM)    ix = i;
            else if (s == LATENT)            ibl = i;
            else if (s == K_CODES * LATENT)  icb = i;
            else if (s == ENC_DIM)           ibd1 = i;
            else if (s == IN_DIM)            ibd2 = i;
            else if (s == IN_DIM * ENC_DIM)  { if (n20 < 2) p20[n20++] = i; }
            else if (s == ENC_DIM * LATENT)  { if (n98 < 2) p98[n98++] = i; }
        }
        iwd2 = p20[0]; iwe = p20[1];
        iwd1 = p98[0]; iwl = p98[1];
    }
    const float* x    = (const float*)d_in[ix];
    const float* Wenc = (const float*)d_in[iwe];
    const float* Wlat = (const float*)d_in[iwl];
    const float* blat = (const float*)d_in[ibl];
    const float* cb   = (const float*)d_in[icb];
    const float* Wd1  = (const float*)d_in[iwd1];
    const float* bd1  = (const float*)d_in[ibd1];
    const float* Wd2  = (const float*)d_in[iwd2];
    const float* bd2  = (const float*)d_in[ibd2];

    float* out = (float*)d_out;
    ushort_t* wcth  = (ushort_t*)d_out + OUT_WCTH_US;
    ushort_t* wctl  = (ushort_t*)d_out + OUT_WCTL_US;
    float*    zpart = out + OUT_ZPART_F;

    float* ws            = (float*)d_ws;
    float* z             = ws + WS_Z;
    float* quant         = ws + WS_QUANT;
    int*   idxp          = (int*)(ws + WS_IDX);
    float* vqpart        = ws + WS_VQPART;
    float* reconpart     = ws + WS_RECON;
    ushort_t* hbf        = (ushort_t*)(ws + WS_HBF);
    ushort_t* wlh        = (ushort_t*)(ws + WS_WLH);
    ushort_t* wll        = (ushort_t*)(ws + WS_WLL);

    const long long obase = (long long)out_size - 258;

    k_prep      <<<96, 256, 0, stream>>>(Wlat, wlh, wll);
    k_wc        <<<NWC, 256, 0, stream>>>(Wenc, wlh, wll, wcth, wctl);
    k_z         <<<dim3(4, NZC), 256, 0, stream>>>(x, wcth, wctl, zpart);
    k_zred      <<<128, 256, 0, stream>>>(zpart, blat, z);
    k_vq        <<<BATCH, 256, 0, stream>>>(z, cb, quant, idxp, vqpart);
    k_h         <<<768, 256, 0, stream>>>(quant, Wd1, bd1, hbf);
    k_recon_mfma<<<NRB, 256, 0, stream>>>(hbf, Wd2, bd2, x, out, reconpart);
    k_final     <<<1, 256, 0, stream>>>(reconpart, vqpart, idxp, out, obase);
}

// Round 9
// 143.592 us; speedup vs baseline: 1.1245x; 1.1245x over previous
//
#include <hip/hip_runtime.h>
#include <hip/hip_bf16.h>

#define IN_DIM   27000
#define ENC_DIM  768
#define LATENT   128
#define K_CODES  512
#define BATCH    256
#define ZCH      288            // k_z split-K chunk (9 K-tiles of 32)
#define NZC      94             // ceil(27000/288); last chunk = 216
#define NWC      422            // k_wc blocks = ceil(27000/64)
#define BN_R     64
#define NRB      422            // k_recon blocks = ceil(27000/64)
#define PADK     40             // LDS k-pitch (ushorts)

// ---- d_out-region scratch (inside x_recon area, 6,912,000 f32 slots) ----
#define OUT_WCTH_US   0                       // ushort offset: [128][27000] hi
#define OUT_WCTL_US   (128*IN_DIM)            // ushort offset: [128][27000] lo
#define OUT_ZPART_F   (128*IN_DIM)            // f32 slot 3,456,000: [94][256][128]
// zpart end = 3,456,000 + 94*32768 = 6,536,192 < 6,912,000 (disjoint from WcT)

// ---- d_ws layout (f32 slots), ~858 KB ----
#define WS_Z      0                          // [256][128] f32
#define WS_QUANT  (WS_Z + BATCH*LATENT)      // [256][128] f32
#define WS_IDX    (WS_QUANT + BATCH*LATENT)  // int[256]
#define WS_VQPART (WS_IDX + BATCH)           // f32[256]
#define WS_RECON  (WS_VQPART + BATCH)        // f32[NRB] (reserve 1024)
#define WS_HBF    (WS_RECON + 1024)          // ushort[256*768] = 49152 slots
#define WS_WLH    (WS_HBF + 49152)           // ushort[128][768] hi (n-major)
#define WS_WLL    (WS_WLH + 49152)           // ushort[128][768] lo

typedef unsigned short ushort_t;
typedef __attribute__((ext_vector_type(4))) float f32x4;
typedef __attribute__((ext_vector_type(8))) short short8x;
typedef __attribute__((ext_vector_type(4))) short short4x;

__device__ __forceinline__ ushort_t bf16_rne(float f) {
    unsigned u = __float_as_uint(f);
    unsigned r = 0x7FFFu + ((u >> 16) & 1u);
    return (ushort_t)((u + r) >> 16);
}
// truncate-hi + rne-lo split: |v - (hi+lo)| <= 2^-17 |v|
__device__ __forceinline__ void split_f32(float v, ushort_t& h, ushort_t& l) {
    unsigned u  = __float_as_uint(v);
    unsigned uh = u & 0xFFFF0000u;
    h = (ushort_t)(uh >> 16);
    l = bf16_rne(v - __uint_as_float(uh));
}

// ============ Kernel 0: pre-split W_lat -> n-major bf16 hi/lo ============
__global__ __launch_bounds__(256) void k_prep(const float* __restrict__ Wlat,
                                              ushort_t* __restrict__ wlh,
                                              ushort_t* __restrict__ wll) {
    const int i4 = blockIdx.x * 256 + threadIdx.x;   // 0..24575
    const int k  = i4 >> 5;                          // 0..767
    const int n4 = (i4 & 31) * 4;
    float4 v = *(const float4*)(Wlat + (size_t)k * LATENT + n4);
    float vv[4] = {v.x, v.y, v.z, v.w};
#pragma unroll
    for (int j = 0; j < 4; j++) {
        ushort_t h, l;
        split_f32(vv[j], h, l);
        wlh[(size_t)(n4 + j) * ENC_DIM + k] = h;
        wll[(size_t)(n4 + j) * ENC_DIM + k] = l;
    }
}

// ============ Kernel 1: WcT = (W_enc @ W_lat)^T as split-bf16 ============
// M=27000, N=128, K=768. LDS double-buffered staging + reg prefetch.
__global__ __launch_bounds__(256) void k_wc(const float* __restrict__ Wenc,
                                            const ushort_t* __restrict__ wlh,
                                            const ushort_t* __restrict__ wll,
                                            ushort_t* __restrict__ wcth,
                                            ushort_t* __restrict__ wctl) {
    __shared__ ushort_t Ah[2][64][PADK], Al[2][64][PADK];    // [buf][m][k]
    __shared__ ushort_t Bh[2][128][PADK], Bl[2][128][PADK];  // [buf][n][k]
    const int t = threadIdx.x, lane = t & 63, w = t >> 6;
    const int lrow = lane & 15, kg = lane >> 4;
    const int m0 = blockIdx.x * 64;

    const int a_row = t >> 3, a_kq = t & 7;   // + p*32 rows; float4 kq
    const int b_n   = t >> 2, b_ck = t & 3;   // + p*64 n;    short8x ck

    float4  areg[2];
    short8x bhreg[2], blreg[2];

    f32x4 acc[8];
#pragma unroll
    for (int ni = 0; ni < 8; ni++) acc[ni] = (f32x4){0.f, 0.f, 0.f, 0.f};

    auto load_tile = [&](int kt) {
        const int k0 = kt * 32;
#pragma unroll
        for (int p = 0; p < 2; p++) {
            int r = m0 + a_row + p * 32; if (r > IN_DIM - 1) r = IN_DIM - 1;
            areg[p] = *(const float4*)(Wenc + (size_t)r * ENC_DIM + k0 + a_kq * 4);
        }
#pragma unroll
        for (int p = 0; p < 2; p++) {
            const size_t bo = (size_t)(b_n + p * 64) * ENC_DIM + k0 + b_ck * 8;
            bhreg[p] = *(const short8x*)(wlh + bo);
            blreg[p] = *(const short8x*)(wll + bo);
        }
    };
    auto store_tile = [&](int bi) {
#pragma unroll
        for (int p = 0; p < 2; p++) {
            const int row = a_row + p * 32;
            float vv[4] = {areg[p].x, areg[p].y, areg[p].z, areg[p].w};
            short4x h4, l4;
#pragma unroll
            for (int i = 0; i < 4; i++) {
                ushort_t h, l; split_f32(vv[i], h, l);
                h4[i] = (short)h; l4[i] = (short)l;
            }
            *(short4x*)&Ah[bi][row][a_kq * 4] = h4;
            *(short4x*)&Al[bi][row][a_kq * 4] = l4;
        }
#pragma unroll
        for (int p = 0; p < 2; p++) {
            const int n = b_n + p * 64;
            *(short8x*)&Bh[bi][n][b_ck * 8] = bhreg[p];
            *(short8x*)&Bl[bi][n][b_ck * 8] = blreg[p];
        }
    };

    load_tile(0);
    store_tile(0);
    __syncthreads();

    for (int kt = 0; kt < ENC_DIM / 32; kt++) {
        if (kt < ENC_DIM / 32 - 1) load_tile(kt + 1);
        const int bi = kt & 1;
        short8x ah = *(const short8x*)&Ah[bi][w * 16 + lrow][kg * 8];
        short8x al = *(const short8x*)&Al[bi][w * 16 + lrow][kg * 8];
#pragma unroll
        for (int ni = 0; ni < 8; ni++) {
            short8x bhf = *(const short8x*)&Bh[bi][ni * 16 + lrow][kg * 8];
            short8x blf = *(const short8x*)&Bl[bi][ni * 16 + lrow][kg * 8];
            acc[ni] = __builtin_amdgcn_mfma_f32_16x16x32_bf16(ah, bhf, acc[ni], 0, 0, 0);
            acc[ni] = __builtin_amdgcn_mfma_f32_16x16x32_bf16(ah, blf, acc[ni], 0, 0, 0);
            acc[ni] = __builtin_amdgcn_mfma_f32_16x16x32_bf16(al, bhf, acc[ni], 0, 0, 0);
        }
        if (kt < ENC_DIM / 32 - 1) store_tile((kt + 1) & 1);
        __syncthreads();
    }

    const int rowb = m0 + w * 16 + kg * 4;   // 4 | 27000: group fully valid or OOB
    if (rowb < IN_DIM) {
#pragma unroll
        for (int ni = 0; ni < 8; ni++) {
            const int col = ni * 16 + lrow;
            short4x h4, l4;
#pragma unroll
            for (int r = 0; r < 4; r++) {
                ushort_t h, l; split_f32(acc[ni][r], h, l);
                h4[r] = (short)h; l4[r] = (short)l;
            }
            *(short4x*)(wcth + (size_t)col * IN_DIM + rowb) = h4;
            *(short4x*)(wctl + (size_t)col * IN_DIM + rowb) = l4;
        }
    }
}

// ============ Kernel 2: zpart = x @ Wc (split-K, 94 chunks of 288) ============
__global__ __launch_bounds__(256) void k_z(const float* __restrict__ x,
                                           const ushort_t* __restrict__ wcth,
                                           const ushort_t* __restrict__ wctl,
                                           float* __restrict__ zpart) {
    __shared__ ushort_t Ah[2][64][PADK], Al[2][64][PADK];
    __shared__ ushort_t Bh[2][128][PADK], Bl[2][128][PADK];
    const int t = threadIdx.x, lane = t & 63, w = t >> 6;
    const int lrow = lane & 15, kg = lane >> 4;
    const int m0 = blockIdx.x * 64;                 // < 256
    const int c  = blockIdx.y;
    const int kb = c * ZCH;
    const int k_end = min(IN_DIM, kb + ZCH);
    const int nt = (k_end - kb + 31) >> 5;          // 9 (7 for last chunk)

    const int a_row = t >> 3, a_kq = t & 7;
    const int b_n   = t >> 2, b_ck = t & 3;

    float4  areg[2];
    short8x bhreg[2], blreg[2];

    f32x4 acc[8];
#pragma unroll
    for (int ni = 0; ni < 8; ni++) acc[ni] = (f32x4){0.f, 0.f, 0.f, 0.f};

    auto load_tile = [&](int kt) {
        const int k0 = kb + kt * 32;
#pragma unroll
        for (int p = 0; p < 2; p++) {
            const int kk = k0 + a_kq * 4;
            if (kk < k_end) {
                const int r = m0 + a_row + p * 32;
                areg[p] = *(const float4*)(x + (size_t)r * IN_DIM + kk);
            } else {
                areg[p] = (float4){0.f, 0.f, 0.f, 0.f};
            }
        }
#pragma unroll
        for (int p = 0; p < 2; p++) {
            const int kk = k0 + b_ck * 8;
            if (kk < k_end) {
                const size_t bo = (size_t)(b_n + p * 64) * IN_DIM + kk;
                bhreg[p] = *(const short8x*)(wcth + bo);
                blreg[p] = *(const short8x*)(wctl + bo);
            } else {
                short8x zz = {0, 0, 0, 0, 0, 0, 0, 0};
                bhreg[p] = zz; blreg[p] = zz;
            }
        }
    };
    auto store_tile = [&](int bi) {
#pragma unroll
        for (int p = 0; p < 2; p++) {
            const int row = a_row + p * 32;
            float vv[4] = {areg[p].x, areg[p].y, areg[p].z, areg[p].w};
            short4x h4, l4;
#pragma unroll
            for (int i = 0; i < 4; i++) {
                ushort_t h, l; split_f32(vv[i], h, l);
                h4[i] = (short)h; l4[i] = (short)l;
            }
            *(short4x*)&Ah[bi][row][a_kq * 4] = h4;
            *(short4x*)&Al[bi][row][a_kq * 4] = l4;
        }
#pragma unroll
        for (int p = 0; p < 2; p++) {
            const int n = b_n + p * 64;
            *(short8x*)&Bh[bi][n][b_ck * 8] = bhreg[p];
            *(short8x*)&Bl[bi][n][b_ck * 8] = blreg[p];
        }
    };

    load_tile(0);
    store_tile(0);
    __syncthreads();

    for (int kt = 0; kt < nt; kt++) {
        if (kt < nt - 1) load_tile(kt + 1);
        const int bi = kt & 1;
        short8x ah = *(const short8x*)&Ah[bi][w * 16 + lrow][kg * 8];
        short8x al = *(const short8x*)&Al[bi][w * 16 + lrow][kg * 8];
#pragma unroll
        for (int ni = 0; ni < 8; ni++) {
            short8x bhf = *(const short8x*)&Bh[bi][ni * 16 + lrow][kg * 8];
            short8x blf = *(const short8x*)&Bl[bi][ni * 16 + lrow][kg * 8];
            acc[ni] = __builtin_amdgcn_mfma_f32_16x16x32_bf16(ah, bhf, acc[ni], 0, 0, 0);
            acc[ni] = __builtin_amdgcn_mfma_f32_16x16x32_bf16(ah, blf, acc[ni], 0, 0, 0);
            acc[ni] = __builtin_amdgcn_mfma_f32_16x16x32_bf16(al, bhf, acc[ni], 0, 0, 0);
        }
        if (kt < nt - 1) store_tile((kt + 1) & 1);
        __syncthreads();
    }

    float* zp = zpart + (size_t)c * (BATCH * LATENT);
    const int rowb = m0 + w * 16 + kg * 4;
#pragma unroll
    for (int ni = 0; ni < 8; ni++) {
        const int col = ni * 16 + lrow;
#pragma unroll
        for (int r = 0; r < 4; r++)
            zp[(size_t)(rowb + r) * LATENT + col] = acc[ni][r];
    }
}

// ============ Kernel 3: z = sum(zpart) + bias ============
__global__ __launch_bounds__(256) void k_zred(const float* __restrict__ zpart,
                                              const float* __restrict__ blat,
                                              float* __restrict__ z) {
    const int o = blockIdx.x * 256 + threadIdx.x;   // < 32768
    float s = blat[o & (LATENT - 1)];
    for (int c = 0; c < NZC; c++) s += zpart[(size_t)c * (BATCH * LATENT) + o];
    z[o] = s;
}

// ============ Kernel 4: VQ — distances, argmin, gather, vq partial ============
__global__ __launch_bounds__(256) void k_vq(const float* __restrict__ z,
                                            const float* __restrict__ cb,
                                            float* __restrict__ quant,
                                            int* __restrict__ idx_out,
                                            float* __restrict__ vqpart) {
    __shared__ float zs[LATENT];
    __shared__ float ds_[256];
    __shared__ int   is_[256];
    const int b = blockIdx.x, t = threadIdx.x;
    if (t < LATENT) zs[t] = z[b * LATENT + t];
    __syncthreads();

    float best_d = 3.4e38f; int best_i = 0;
#pragma unroll
    for (int rep = 0; rep < 2; rep++) {
        const int k = t + rep * 256;
        const float* e = cb + (size_t)k * LATENT;
        float acc = 0.f;
#pragma unroll 4
        for (int d = 0; d < LATENT; d += 4) {
            float4 ev = *(const float4*)(e + d);
            float d0 = zs[d]   - ev.x;
            float d1 = zs[d+1] - ev.y;
            float d2 = zs[d+2] - ev.z;
            float d3 = zs[d+3] - ev.w;
            acc += d0*d0 + d1*d1 + d2*d2 + d3*d3;
        }
        if (acc < best_d) { best_d = acc; best_i = k; }
    }
    ds_[t] = best_d; is_[t] = best_i;
    __syncthreads();
    for (int s = 128; s > 0; s >>= 1) {
        if (t < s) {
            float od = ds_[t+s]; int oi = is_[t+s];
            if (od < ds_[t] || (od == ds_[t] && oi < is_[t])) { ds_[t] = od; is_[t] = oi; }
        }
        __syncthreads();
    }
    const int best = is_[0];
    if (t == 0) idx_out[b] = best;

    float sq = 0.f;
    if (t < LATENT) {
        float q = cb[(size_t)best * LATENT + t];
        quant[b * LATENT + t] = q;
        float dd = q - zs[t];
        sq = dd * dd;
    }
    __syncthreads();
    ds_[t] = sq;
    __syncthreads();
    for (int s = 128; s > 0; s >>= 1) {
        if (t < s) ds_[t] += ds_[t+s];
        __syncthreads();
    }
    if (t == 0) vqpart[b] = ds_[0];
}

// ============ Kernel 5: h = relu(quant @ W_d1 + b_d1) -> bf16 ============
__global__ __launch_bounds__(256) void k_h(const float* __restrict__ quant,
                                           const float* __restrict__ Wd1,
                                           const float* __restrict__ bd1,
                                           ushort_t* __restrict__ hbf) {
    const int bid = blockIdx.x, t = threadIdx.x;
    const int row = bid / 3;
    const int col = (bid % 3) * 256 + t;
    float acc = bd1[col];
    const float* q = quant + row * LATENT;
#pragma unroll 8
    for (int k = 0; k < LATENT; k++)
        acc = fmaf(q[k], Wd1[(size_t)k * ENC_DIM + col], acc);
    hbf[(size_t)row * ENC_DIM + col] = bf16_rne(fmaxf(acc, 0.f));
}

// ============ Kernel 6: x_recon = h @ W_d2 + b_d2 + fused loss ============
// k_wc-mold: BM=256, BN=64, grid 422, 4 waves (wave 64x64), dbuf + reg prefetch.
// A (hbf, bf16): 1 row/thread, 4x short8x, no conversion. B (Wd2): k-consecutive
// 8 coalesced f32 loads/thread -> one short8x LDS store (conflict-free pattern).
__global__ __launch_bounds__(256) void k_recon_mfma(const ushort_t* __restrict__ hbf,
                                                    const float* __restrict__ Wd2,
                                                    const float* __restrict__ bd2,
                                                    const float* __restrict__ x,
                                                    float* __restrict__ out,
                                                    float* __restrict__ reconpart) {
    __shared__ ushort_t Ahs[2][256][PADK];    // 40960 B
    __shared__ ushort_t Bts[2][BN_R][PADK];   // 10240 B
    __shared__ float red[256];
    const int t = threadIdx.x, lane = t & 63, wid = t >> 6;
    const int lrow = lane & 15, kg = lane >> 4;
    const int n0 = blockIdx.x * BN_R;

    const int a_row = t;             // one 64B row slice per thread
    const int b_n  = t & 63;         // col within tile
    const int b_kq = t >> 6;         // 0..3 -> k-offset 8*b_kq
    const bool bvalid = (n0 + b_n) < IN_DIM;

    f32x4 acc[4][4];
#pragma unroll
    for (int mi = 0; mi < 4; mi++)
#pragma unroll
        for (int ni = 0; ni < 4; ni++) acc[mi][ni] = (f32x4){0.f, 0.f, 0.f, 0.f};

    short8x areg[4];
    float   bregs[8];

    auto load_tile = [&](int kt) {
        const int k0 = kt * 32;
        const ushort_t* ap = hbf + (size_t)a_row * ENC_DIM + k0;
        areg[0] = *(const short8x*)(ap);
        areg[1] = *(const short8x*)(ap + 8);
        areg[2] = *(const short8x*)(ap + 16);
        areg[3] = *(const short8x*)(ap + 24);
        if (bvalid) {
            const float* wp = Wd2 + (size_t)(k0 + b_kq * 8) * IN_DIM + n0 + b_n;
#pragma unroll
            for (int j = 0; j < 8; j++) bregs[j] = wp[(size_t)j * IN_DIM];
        } else {
#pragma unroll
            for (int j = 0; j < 8; j++) bregs[j] = 0.f;
        }
    };
    auto store_tile = [&](int bi) {
#pragma unroll
        for (int q = 0; q < 4; q++)
            *(short8x*)&Ahs[bi][a_row][q * 8] = areg[q];
        short8x bb;
#pragma unroll
        for (int j = 0; j < 8; j++) bb[j] = (short)bf16_rne(bregs[j]);
        *(short8x*)&Bts[bi][b_n][b_kq * 8] = bb;
    };

    load_tile(0);
    store_tile(0);
    __syncthreads();

    for (int kt = 0; kt < ENC_DIM / 32; kt++) {
        if (kt < ENC_DIM / 32 - 1) load_tile(kt + 1);
        const int bi = kt & 1;
        short8x a[4], b[4];
#pragma unroll
        for (int mi = 0; mi < 4; mi++)
            a[mi] = *(const short8x*)&Ahs[bi][wid * 64 + mi * 16 + lrow][kg * 8];
#pragma unroll
        for (int ni = 0; ni < 4; ni++)
            b[ni] = *(const short8x*)&Bts[bi][ni * 16 + lrow][kg * 8];
#pragma unroll
        for (int mi = 0; mi < 4; mi++)
#pragma unroll
            for (int ni = 0; ni < 4; ni++)
                acc[mi][ni] = __builtin_amdgcn_mfma_f32_16x16x32_bf16(a[mi], b[ni], acc[mi][ni], 0, 0, 0);
        if (kt < ENC_DIM / 32 - 1) store_tile((kt + 1) & 1);
        __syncthreads();
    }

    float lsq = 0.f;
#pragma unroll
    for (int mi = 0; mi < 4; mi++) {
        const int rowb = wid * 64 + mi * 16 + kg * 4;
#pragma unroll
        for (int ni = 0; ni < 4; ni++) {
            const int col = n0 + ni * 16 + lrow;
            if (col < IN_DIM) {
                const float bb = bd2[col];
#pragma unroll
                for (int r = 0; r < 4; r++) {
                    const int row = rowb + r;
                    float v = acc[mi][ni][r] + bb;
                    float e = v - x[(size_t)row * IN_DIM + col];
                    lsq += e * e;
                    out[(size_t)row * IN_DIM + col] = v;
                }
            }
        }
    }

    red[t] = lsq;
    __syncthreads();
    for (int s = 128; s > 0; s >>= 1) {
        if (t < s) red[t] += red[t + s];
        __syncthreads();
    }
    if (t == 0) reconpart[blockIdx.x] = red[0];
}

// ============ Kernel 7: finalize losses + indices (f32) ============
__global__ __launch_bounds__(256) void k_final(const float* __restrict__ reconpart,
                                               const float* __restrict__ vqpart,
                                               const int* __restrict__ idx,
                                               float* __restrict__ out,
                                               long long obase) {
    __shared__ float red[256];
    const int t = threadIdx.x;
    float s = 0.f;
    for (int i = t; i < NRB; i += 256) s += reconpart[i];
    red[t] = s;
    __syncthreads();
    for (int st = 128; st > 0; st >>= 1) {
        if (t < st) red[t] += red[t + st];
        __syncthreads();
    }
    const float recon_sum = red[0];
    __syncthreads();
    red[t] = vqpart[t];
    __syncthreads();
    for (int st = 128; st > 0; st >>= 1) {
        if (t < st) red[t] += red[t + st];
        __syncthreads();
    }
    const float vq_sum = red[0];
    if (t == 0) {
        float recon_loss = recon_sum / (float)((size_t)BATCH * IN_DIM);
        float vq_loss = 1.1f * vq_sum / (float)(BATCH * LATENT);
        out[obase + 0] = recon_loss + vq_loss;
        out[obase + 1] = vq_loss;
    }
    out[obase + 2 + t] = (float)idx[t];
}

extern "C" void kernel_launch(void* const* d_in, const int* in_sizes, int n_in,
                              void* d_out, int out_size, void* d_ws, size_t ws_size,
                              hipStream_t stream) {
    int ix = 0, iwe = 1, iwl = 2, ibl = 3, icb = 4, iwd1 = 5, ibd1 = 6, iwd2 = 7, ibd2 = 8;
    if (n_in == 9 && in_sizes[0] != BATCH * IN_DIM) {
        int p20[2] = {1, 7}, n20 = 0, p98[2] = {2, 5}, n98 = 0;
        for (int i = 0; i < 9; i++) {
            const int s = in_sizes[i];
            if      (s == BATCH * IN_DIM)    ix = i;
            else if (s == LATENT)            ibl = i;
            else if (s == K_CODES * LATENT)  icb = i;
            else if (s == ENC_DIM)           ibd1 = i;
            else if (s == IN_DIM)            ibd2 = i;
            else if (s == IN_DIM * ENC_DIM)  { if (n20 < 2) p20[n20++] = i; }
            else if (s == ENC_DIM * LATENT)  { if (n98 < 2) p98[n98++] = i; }
        }
        iwd2 = p20[0]; iwe = p20[1];
        iwd1 = p98[0]; iwl = p98[1];
    }
    const float* x    = (const float*)d_in[ix];
    const float* Wenc = (const float*)d_in[iwe];
    const float* Wlat = (const float*)d_in[iwl];
    const float* blat = (const float*)d_in[ibl];
    const float* cb   = (const float*)d_in[icb];
    const float* Wd1  = (const float*)d_in[iwd1];
    const float* bd1  = (const float*)d_in[ibd1];
    const float* Wd2  = (const float*)d_in[iwd2];
    const float* bd2  = (const float*)d_in[ibd2];

    float* out = (float*)d_out;
    ushort_t* wcth  = (ushort_t*)d_out + OUT_WCTH_US;
    ushort_t* wctl  = (ushort_t*)d_out + OUT_WCTL_US;
    float*    zpart = out + OUT_ZPART_F;

    float* ws            = (float*)d_ws;
    float* z             = ws + WS_Z;
    float* quant         = ws + WS_QUANT;
    int*   idxp          = (int*)(ws + WS_IDX);
    float* vqpart        = ws + WS_VQPART;
    float* reconpart     = ws + WS_RECON;
    ushort_t* hbf        = (ushort_t*)(ws + WS_HBF);
    ushort_t* wlh        = (ushort_t*)(ws + WS_WLH);
    ushort_t* wll        = (ushort_t*)(ws + WS_WLL);

    const long long obase = (long long)out_size - 258;

    k_prep      <<<96, 256, 0, stream>>>(Wlat, wlh, wll);
    k_wc        <<<NWC, 256, 0, stream>>>(Wenc, wlh, wll, wcth, wctl);
    k_z         <<<dim3(4, NZC), 256, 0, stream>>>(x, wcth, wctl, zpart);
    k_zred      <<<128, 256, 0, stream>>>(zpart, blat, z);
    k_vq        <<<BATCH, 256, 0, stream>>>(z, cb, quant, idxp, vqpart);
    k_h         <<<768, 256, 0, stream>>>(quant, Wd1, bd1, hbf);
    k_recon_mfma<<<NRB, 256, 0, stream>>>(hbf, Wd2, bd2, x, out, reconpart);
    k_final     <<<1, 256, 0, stream>>>(reconpart, vqpart, idxp, out, obase);
}